// Round 17
// baseline (981.897 us; speedup 1.0000x reference)
//
#include <hip/hip_runtime.h>

constexpr int Tq = 2048;
constexpr int Dq = 1024;

typedef __bf16 bf16x8 __attribute__((ext_vector_type(8)));
typedef float f32x4 __attribute__((ext_vector_type(4)));
typedef _Float16 f16;
typedef f16 f16x4 __attribute__((ext_vector_type(4)));
typedef unsigned short u16;
typedef u16 u16x4 __attribute__((ext_vector_type(4)));
typedef u16 u16x8 __attribute__((ext_vector_type(8)));

__device__ __forceinline__ u16 f2bf(float f) {
    unsigned int u = __float_as_uint(f);
    u += 0x7fffu + ((u >> 16) & 1u);   // RNE
    return (u16)(u >> 16);
}

// async global->LDS, 16B per lane. LDS dest must be wave-uniform base + lane*16.
__device__ __forceinline__ void gld_lds16(const void* g, void* l) {
    __builtin_amdgcn_global_load_lds(
        (const __attribute__((address_space(1))) unsigned int*)g,
        (__attribute__((address_space(3))) unsigned int*)l, 16, 0, 0);
}

// ---------------- fp32 -> bf16 conversion (3 arrays, one launch) ------------
__global__ void cvt3_f32_bf16(const float* __restrict__ a, u16* __restrict__ oa, int na,
                              const float* __restrict__ b, u16* __restrict__ ob, int nb,
                              const float* __restrict__ c, u16* __restrict__ oc, int nc) {
    int i = blockIdx.x * 256 + threadIdx.x;
    const float* in; u16* out;
    if (i < na) { in = a; out = oa; }
    else if (i < na + nb) { in = b; out = ob; i -= na; }
    else if (i < na + nb + nc) { in = c; out = oc; i -= na + nb; }
    else return;
    float4 v = ((const float4*)in)[i];
    u16x4 o;
    o.x = f2bf(v.x); o.y = f2bf(v.y); o.z = f2bf(v.z); o.w = f2bf(v.w);
    ((u16x4*)out)[i] = o;
}

// ---------------- QKV GEMM with fused RoPE + scatter epilogue ----------------
// C[8192,3072] = xb * Wqkv^T. blockIdx.y: 0..7 -> Q (rope+scale), 8..15 -> K
// (rope), 16..23 -> V (transposed f16). A 128-col tile never straddles Q/K/V,
// and d & d+32 of one head land in the SAME lane (sub-tiles j and j+2).
__global__ __launch_bounds__(256) void gemm_qkv(const u16* __restrict__ A,
                                                const u16* __restrict__ B,
                                                const float* __restrict__ cosT,
                                                const float* __restrict__ sinT,
                                                u16* __restrict__ Qb,
                                                u16* __restrict__ Kb,
                                                f16* __restrict__ Vtg) {
    constexpr int K = 1024, N = 3072;
    __shared__ u16 As[128 * 32];
    __shared__ u16 Bs[128 * 32];
    const int t = threadIdx.x;
    const int lane = t & 63;
    const int wave = t >> 6;
    const int l16 = lane & 15;
    const int quad = lane >> 4;
    const int bm = blockIdx.x * 128;
    const int by = blockIdx.y;
    const int bn = by * 128;
    const int wm = (wave & 1) * 64;
    const int wn = (wave >> 1) * 64;
    const int srow = t >> 2;
    const int scol = (t & 3) * 8;

    f32x4 acc[4][4] = {};

    const u16* Ab = A + (size_t)(bm + srow) * K + scol;
    const u16* Bb = B + (size_t)(bn + srow) * K + scol;

    for (int k0 = 0; k0 < K; k0 += 32) {
        gld_lds16(Ab + k0,                    (char*)As + t * 16);
        gld_lds16(Ab + (size_t)64 * K + k0,   (char*)As + 4096 + t * 16);
        gld_lds16(Bb + k0,                    (char*)Bs + t * 16);
        gld_lds16(Bb + (size_t)64 * K + k0,   (char*)Bs + 4096 + t * 16);
        __syncthreads();

        bf16x8 af[4], bf[4];
#pragma unroll
        for (int i = 0; i < 4; i++) {
            af[i] = *(const bf16x8*)&As[(wm + i * 16 + l16) * 32 + quad * 8];
            bf[i] = *(const bf16x8*)&Bs[(wn + i * 16 + l16) * 32 + quad * 8];
        }
#pragma unroll
        for (int i = 0; i < 4; i++)
#pragma unroll
            for (int j = 0; j < 4; j++)
                acc[i][j] = __builtin_amdgcn_mfma_f32_16x16x32_bf16(af[i], bf[j], acc[i][j], 0, 0, 0);
        __syncthreads();
    }

    const int kind = by >> 3;                   // 0=Q 1=K 2=V
    if (kind < 2) {
        // rope: pairs (j, j+2) give (d, d+32) of head h in the same lane
        u16* Out = kind ? Kb : Qb;
        const float qscale = kind ? 1.f : 0.18033688011112042f;  // 0.125*log2(e)
        const int h = ((by & 7) << 1) + (wn >> 6);
#pragma unroll
        for (int i = 0; i < 4; i++)
#pragma unroll
            for (int r = 0; r < 4; r++) {
                const int gm = bm + wm + i * 16 + quad * 4 + r;
                const int b = gm >> 11, tt = gm & 2047;
                const size_t row = ((size_t)(b * 16 + h) * Tq + tt) * 64;
#pragma unroll
                for (int jj = 0; jj < 2; jj++) {
                    const int dd = jj * 16 + l16;            // 0..31
                    const float c = cosT[tt * 32 + dd];
                    const float s = sinT[tt * 32 + dd];
                    const float v1 = acc[i][jj][r];
                    const float v2 = acc[i][jj + 2][r];
                    Out[row + dd]      = f2bf((v1 * c - v2 * s) * qscale);
                    Out[row + dd + 32] = f2bf((v1 * s + v2 * c) * qscale);
                }
            }
    } else {
        // V: write transposed (bh, d, t) in f16; f16x4 contiguous along t
#pragma unroll
        for (int i = 0; i < 4; i++) {
            const int gm0 = bm + wm + i * 16 + quad * 4;
            const int b = gm0 >> 11, tt = gm0 & 2047;
#pragma unroll
            for (int j = 0; j < 4; j++) {
                const int col = wn + j * 16 + l16;           // 0..127
                const int h = ((by & 7) << 1) + (col >> 6);
                const int d = col & 63;
                f16x4 o = {(f16)acc[i][j][0], (f16)acc[i][j][1],
                           (f16)acc[i][j][2], (f16)acc[i][j][3]};
                *(f16x4*)&Vtg[((size_t)(b * 16 + h) * 64 + d) * Tq + tt] = o;
            }
        }
    }
}

// ---------------- GEMM: C[M,N] = A[M,K] * B[N,K]^T (m97 structure) ----------
__global__ __launch_bounds__(256) void gemm_bt(const u16* __restrict__ A,
                                               const u16* __restrict__ B,
                                               float* __restrict__ Cv,
                                               int M, int N, int K) {
    __shared__ u16 As[128 * 32];
    __shared__ u16 Bs[128 * 32];
    const int t = threadIdx.x;
    const int lane = t & 63;
    const int wave = t >> 6;
    const int l16 = lane & 15;
    const int quad = lane >> 4;
    const int bm = blockIdx.x * 128;
    const int bn = blockIdx.y * 128;
    const int wm = (wave & 1) * 64;
    const int wn = (wave >> 1) * 64;
    const int srow = t >> 2;
    const int scol = (t & 3) * 8;

    f32x4 acc[4][4] = {};

    const u16* Ab = A + (size_t)(bm + srow) * K + scol;
    const u16* Bb = B + (size_t)(bn + srow) * K + scol;

    for (int k0 = 0; k0 < K; k0 += 32) {
        gld_lds16(Ab + k0,                    (char*)As + t * 16);
        gld_lds16(Ab + (size_t)64 * K + k0,   (char*)As + 4096 + t * 16);
        gld_lds16(Bb + k0,                    (char*)Bs + t * 16);
        gld_lds16(Bb + (size_t)64 * K + k0,   (char*)Bs + 4096 + t * 16);
        __syncthreads();

        bf16x8 af[4], bf[4];
#pragma unroll
        for (int i = 0; i < 4; i++) {
            af[i] = *(const bf16x8*)&As[(wm + i * 16 + l16) * 32 + quad * 8];
            bf[i] = *(const bf16x8*)&Bs[(wn + i * 16 + l16) * 32 + quad * 8];
        }
#pragma unroll
        for (int i = 0; i < 4; i++)
#pragma unroll
            for (int j = 0; j < 4; j++)
                acc[i][j] = __builtin_amdgcn_mfma_f32_16x16x32_bf16(af[i], bf[j], acc[i][j], 0, 0, 0);
        __syncthreads();
    }

#pragma unroll
    for (int i = 0; i < 4; i++)
#pragma unroll
        for (int j = 0; j < 4; j++)
#pragma unroll
            for (int r = 0; r < 4; r++) {
                const int gm = bm + wm + i * 16 + quad * 4 + r;
                const int gn = bn + wn + j * 16 + l16;
                Cv[(size_t)gm * N + gn] = acc[i][j][r];
            }
}

// ---------------- flash attention: S^T form, constant-max softmax -----------
// Softmax for one stream's 16 S-values (statically indexed array). diag is
// block-uniform: branch selects masked vs plain unrolled loop.
#define SMAX(S, LR, DIAG)                                                     \
    do {                                                                      \
        float ra_ = 0.f;                                                      \
        if (DIAG) {                                                           \
            _Pragma("unroll") for (int tn_ = 0; tn_ < 4; tn_++)               \
                _Pragma("unroll") for (int r_ = 0; r_ < 4; r_++) {            \
                    const int jl_ = tn_ * 16 + quad * 4 + r_;                 \
                    float v_ = S[tn_][r_];                                    \
                    if (jl_ > i_loc) v_ = -1e30f;                             \
                    float p_ = exp2f(v_);                                     \
                    ra_ += p_;                                                \
                    if (jl_ == i_loc) p_ = 0.f;                               \
                    S[tn_][r_] = p_;                                          \
                }                                                             \
        } else {                                                              \
            _Pragma("unroll") for (int tn_ = 0; tn_ < 4; tn_++)               \
                _Pragma("unroll") for (int r_ = 0; r_ < 4; r_++) {            \
                    float p_ = exp2f(S[tn_][r_]);                             \
                    ra_ += p_;                                                \
                    S[tn_][r_] = p_;                                          \
                }                                                             \
        }                                                                     \
        LR += ra_;                                                            \
    } while (0)

// Quad-stream tile: ONE kf/vf LDS load set feeds up to FOUR q-streams' MFMAs.
// Extends the measured tile2 mechanism (conflicts -25% -> time -7.5%): LDS
// bytes per MFMA is the knob. Stream 3 (largest qt) is always active within
// the loop range; 0..2 gated by block-uniform bools (no wasted MFMA).
__device__ __forceinline__ void flash_tile4(
    const u16* __restrict__ Ks, const f16* __restrict__ Vs, int tile,
    int qt0, int qt1, int qt2, int qt3,
    const bf16x8& q00, const bf16x8& q01, const bf16x8& q10, const bf16x8& q11,
    const bf16x8& q20, const bf16x8& q21, const bf16x8& q30, const bf16x8& q31,
    int l16, int quad, int i_loc,
    float& l0, f32x4* o0, float& l1, f32x4* o1,
    float& l2, f32x4* o2, float& l3, f32x4* o3) {
    const bool a0 = tile <= qt0, a1 = tile <= qt1, a2 = tile <= qt2;
    const bool d0 = tile == qt0, d1 = tile == qt1, d2 = tile == qt2, d3 = tile == qt3;
    f32x4 s0[4], s1[4], s2[4], s3[4];
    const int cp0 = quad ^ (l16 & 7);
    const int cp1 = (4 + quad) ^ (l16 & 7);
    __builtin_amdgcn_s_setprio(1);
#pragma unroll
    for (int tn = 0; tn < 4; tn++) {
        const int jrow = tn * 16 + l16;
        bf16x8 kf0 = *(const bf16x8*)&Ks[jrow * 64 + cp0 * 8];
        bf16x8 kf1 = *(const bf16x8*)&Ks[jrow * 64 + cp1 * 8];
        f32x4 z = {0.f, 0.f, 0.f, 0.f};
        z = __builtin_amdgcn_mfma_f32_16x16x32_bf16(kf0, q30, z, 0, 0, 0);
        z = __builtin_amdgcn_mfma_f32_16x16x32_bf16(kf1, q31, z, 0, 0, 0);
        s3[tn] = z;
        if (a2) {
            f32x4 z2 = {0.f, 0.f, 0.f, 0.f};
            z2 = __builtin_amdgcn_mfma_f32_16x16x32_bf16(kf0, q20, z2, 0, 0, 0);
            z2 = __builtin_amdgcn_mfma_f32_16x16x32_bf16(kf1, q21, z2, 0, 0, 0);
            s2[tn] = z2;
        }
        if (a1) {
            f32x4 z1 = {0.f, 0.f, 0.f, 0.f};
            z1 = __builtin_amdgcn_mfma_f32_16x16x32_bf16(kf0, q10, z1, 0, 0, 0);
            z1 = __builtin_amdgcn_mfma_f32_16x16x32_bf16(kf1, q11, z1, 0, 0, 0);
            s1[tn] = z1;
        }
        if (a0) {
            f32x4 z0 = {0.f, 0.f, 0.f, 0.f};
            z0 = __builtin_amdgcn_mfma_f32_16x16x32_bf16(kf0, q00, z0, 0, 0, 0);
            z0 = __builtin_amdgcn_mfma_f32_16x16x32_bf16(kf1, q01, z0, 0, 0, 0);
            s0[tn] = z0;
        }
    }
    __builtin_amdgcn_s_setprio(0);

    SMAX(s3, l3, d3);
    if (a2) SMAX(s2, l2, d2);
    if (a1) SMAX(s1, l1, d1);
    if (a0) SMAX(s0, l0, d0);

    f16x4 pf0[4], pf1[4], pf2[4], pf3[4];
#pragma unroll
    for (int tk = 0; tk < 4; tk++)
        pf3[tk] = f16x4{(f16)s3[tk][0], (f16)s3[tk][1], (f16)s3[tk][2], (f16)s3[tk][3]};
    if (a2) {
#pragma unroll
        for (int tk = 0; tk < 4; tk++)
            pf2[tk] = f16x4{(f16)s2[tk][0], (f16)s2[tk][1], (f16)s2[tk][2], (f16)s2[tk][3]};
    }
    if (a1) {
#pragma unroll
        for (int tk = 0; tk < 4; tk++)
            pf1[tk] = f16x4{(f16)s1[tk][0], (f16)s1[tk][1], (f16)s1[tk][2], (f16)s1[tk][3]};
    }
    if (a0) {
#pragma unroll
        for (int tk = 0; tk < 4; tk++)
            pf0[tk] = f16x4{(f16)s0[tk][0], (f16)s0[tk][1], (f16)s0[tk][2], (f16)s0[tk][3]};
    }
    __builtin_amdgcn_s_setprio(1);
#pragma unroll
    for (int td = 0; td < 4; td++) {
        const int drow = td * 16 + l16;
#pragma unroll
        for (int tk = 0; tk < 4; tk++) {
            const int cp = (2 * tk + (quad >> 1)) ^ (l16 & 7);
            f16x4 vf = *(const f16x4*)&Vs[drow * 64 + cp * 8 + (quad & 1) * 4];
            o3[td] = __builtin_amdgcn_mfma_f32_16x16x16f16(vf, pf3[tk], o3[td], 0, 0, 0);
            if (a2) o2[td] = __builtin_amdgcn_mfma_f32_16x16x16f16(vf, pf2[tk], o2[td], 0, 0, 0);
            if (a1) o1[td] = __builtin_amdgcn_mfma_f32_16x16x16f16(vf, pf1[tk], o1[td], 0, 0, 0);
            if (a0) o0[td] = __builtin_amdgcn_mfma_f32_16x16x16f16(vf, pf0[tk], o0[td], 0, 0, 0);
        }
    }
    __builtin_amdgcn_s_setprio(0);
}

// 256 threads = 4 waves. Each block owns FOUR q-tiles = two complementary
// pairs {x, x+8, 23-x, 31-x}, x in 0..7 (exact partition of 0..31; per-block
// work = 66 tiles, constant). Each wave holds the same 16-row slice of all 4
// tiles; flash_tile4 shares each kf/vf load across up to 4 streams -> LDS
// reads -42% vs tile2 (228 vs 392 load-set iterations per head). Grid = 512
// blocks = exactly 2 blocks/CU x 256 CUs, single occupancy round, same L2
// pressure as the measured-best config. Ring-2 KVBLK=128 staging, gates, and
// swizzle unchanged from the verified tile2 kernel.
// XCD-swizzled: head bh entirely on XCD bh>>3 (KV working set = 4MB = L2).
__global__ __launch_bounds__(256, 2) void flash(const u16* __restrict__ Qb,
                                                const u16* __restrict__ Kb,
                                                const f16* __restrict__ Vtg,
                                                u16* __restrict__ Ob) {
    __shared__ __align__(16) char smem[65536];   // 2 x 32KB

    const int t = threadIdx.x, lane = t & 63, wave = t >> 6;   // wave 0..3
    const int l16 = lane & 15, quad = lane >> 4;
    const int i = blockIdx.x;                    // 0..511
    const int xcd = i & 7, w = i >> 3;           // w: 0..63
    const int bh = xcd * 8 + (w >> 3);           // 8 heads per XCD
    const int b = bh >> 4, h = bh & 15;
    const int x = w & 7;
    const int qt0 = x, qt1 = x + 8, qt2 = 23 - x, qt3 = 31 - x;
    const u16* Qp = Qb + (size_t)bh * Tq * 64;
    const u16* Kp = Kb + (size_t)bh * Tq * 64;
    const f16* Vp = Vtg + (size_t)bh * 64 * Tq;

    const int rowi = wave * 16 + l16;            // row slice within each tile
    bf16x8 q00 = *(const bf16x8*)(Qp + (size_t)(qt0 * 64 + rowi) * 64 + quad * 8);
    bf16x8 q01 = *(const bf16x8*)(Qp + (size_t)(qt0 * 64 + rowi) * 64 + 32 + quad * 8);
    bf16x8 q10 = *(const bf16x8*)(Qp + (size_t)(qt1 * 64 + rowi) * 64 + quad * 8);
    bf16x8 q11 = *(const bf16x8*)(Qp + (size_t)(qt1 * 64 + rowi) * 64 + 32 + quad * 8);
    bf16x8 q20 = *(const bf16x8*)(Qp + (size_t)(qt2 * 64 + rowi) * 64 + quad * 8);
    bf16x8 q21 = *(const bf16x8*)(Qp + (size_t)(qt2 * 64 + rowi) * 64 + 32 + quad * 8);
    bf16x8 q30 = *(const bf16x8*)(Qp + (size_t)(qt3 * 64 + rowi) * 64 + quad * 8);
    bf16x8 q31 = *(const bf16x8*)(Qp + (size_t)(qt3 * 64 + rowi) * 64 + 32 + quad * 8);
    // pin Q-frag loads complete so manual vmcnt bookkeeping below is exact
    asm volatile("s_waitcnt vmcnt(0)"
                 : "+v"(q00), "+v"(q01), "+v"(q10), "+v"(q11),
                   "+v"(q20), "+v"(q21), "+v"(q30), "+v"(q31) :: "memory");

    float l0 = 0.f, l1 = 0.f, l2 = 0.f, l3 = 0.f;
    f32x4 o0[4] = {}, o1[4] = {}, o2[4] = {}, o3[4] = {};

    const int sr = t >> 3;                       // 0..31 (256 threads)
    const int sc = (t & 7) ^ (sr & 7);           // swizzled chunk slot
    const int i_tloc = wave * 16 + l16;          // query pos within any tile
    const int nt = 32 - x;                       // loop covers tiles 0..qt3
    const int nt2 = (nt + 1) >> 1;               // 128-iterations (13..16)

    auto stage = [&](int n2) {                   // 8 loads -> vmcnt +8
        const int j0 = n2 * 128;                 // staged rows <= 2047: in-bounds
        char* buf = smem + (n2 & 1) * 32768;
        gld_lds16(Kp + (size_t)(j0 + sr) * 64 + sc * 8,            buf + t * 16);
        gld_lds16(Kp + (size_t)(j0 + 32 + sr) * 64 + sc * 8,       buf + 4096 + t * 16);
        gld_lds16(Kp + (size_t)(j0 + 64 + sr) * 64 + sc * 8,       buf + 8192 + t * 16);
        gld_lds16(Kp + (size_t)(j0 + 96 + sr) * 64 + sc * 8,       buf + 12288 + t * 16);
        gld_lds16(Vp + (size_t)sr * Tq + j0 + sc * 8,              buf + 16384 + t * 16);
        gld_lds16(Vp + (size_t)(32 + sr) * Tq + j0 + sc * 8,       buf + 20480 + t * 16);
        gld_lds16(Vp + (size_t)sr * Tq + j0 + 64 + sc * 8,         buf + 24576 + t * 16);
        gld_lds16(Vp + (size_t)(32 + sr) * Tq + j0 + 64 + sc * 8,  buf + 28672 + t * 16);
    };

    stage(0);
    for (int n2 = 0; n2 < nt2; n2++) {
        // gate: stage(n2) retired (issued a full iteration ago)
        asm volatile("s_waitcnt vmcnt(0)\n\ts_barrier" ::: "memory");
        if (n2 + 1 < nt2) stage(n2 + 1);         // post-barrier: WAR-safe ring-2
        char* cb = smem + (n2 & 1) * 32768;
#pragma unroll
        for (int s = 0; s < 2; s++) {
            const int tile = n2 * 2 + s;
            if (tile <= qt3) {                   // block-uniform (odd-nt tail)
                const u16* Ks = (const u16*)(cb + s * 8192);
                const f16* Vs = (const f16*)(cb + 16384 + s * 8192);
                flash_tile4(Ks, Vs, tile, qt0, qt1, qt2, qt3,
                            q00, q01, q10, q11, q20, q21, q30, q31,
                            l16, quad, i_tloc, l0, o0, l1, o1, l2, o2, l3, o3);
            }
        }
    }

    // reduce l across the 4 quads sharing each query (once, not per tile)
    l0 += __shfl_xor(l0, 16, 64); l0 += __shfl_xor(l0, 32, 64);
    l1 += __shfl_xor(l1, 16, 64); l1 += __shfl_xor(l1, 32, 64);
    l2 += __shfl_xor(l2, 16, 64); l2 += __shfl_xor(l2, 32, 64);
    l3 += __shfl_xor(l3, 16, 64); l3 += __shfl_xor(l3, 32, 64);
    const float iv0 = 1.f / l0, iv1 = 1.f / l1, iv2 = 1.f / l2, iv3 = 1.f / l3;

    // epilogue: O^T -> O via padded LDS (stride 72), coalesced bf16 stores.
    // 16 slots (4 waves x 4 streams) * 1152 u16 = 36KB.
    __syncthreads();                             // all waves done reading ring
    u16* Os = (u16*)smem;
#pragma unroll
    for (int td = 0; td < 4; td++) {
        u16x4 w0, w1, w2, w3;
#pragma unroll
        for (int r = 0; r < 4; r++) {
            w0[r] = f2bf(o0[td][r] * iv0);
            w1[r] = f2bf(o1[td][r] * iv1);
            w2[r] = f2bf(o2[td][r] * iv2);
            w3[r] = f2bf(o3[td][r] * iv3);
        }
        const int base = l16 * 72 + td * 16 + quad * 4;
        *(u16x4*)&Os[(0 * 4 + wave) * 1152 + base] = w0;
        *(u16x4*)&Os[(1 * 4 + wave) * 1152 + base] = w1;
        *(u16x4*)&Os[(2 * 4 + wave) * 1152 + base] = w2;
        *(u16x4*)&Os[(3 * 4 + wave) * 1152 + base] = w3;
    }
    __syncthreads();
    const int oi = lane >> 2, od = (lane & 3) * 16;
#pragma unroll
    for (int s = 0; s < 4; s++) {
        const int qts = (s == 0) ? qt0 : (s == 1) ? qt1 : (s == 2) ? qt2 : qt3;
        u16x8 r0 = *(const u16x8*)&Os[(s * 4 + wave) * 1152 + oi * 72 + od];
        u16x8 r1 = *(const u16x8*)&Os[(s * 4 + wave) * 1152 + oi * 72 + od + 8];
        const size_t orow = ((size_t)b * Tq + qts * 64 + wave * 16 + oi) * Dq + h * 64 + od;
        *(u16x8*)&Ob[orow] = r0;
        *(u16x8*)&Ob[orow + 8] = r1;
    }
}

// ---------------- launch ----------------
extern "C" void kernel_launch(void* const* d_in, const int* in_sizes, int n_in,
                              void* d_out, int out_size, void* d_ws, size_t ws_size,
                              hipStream_t stream) {
    const float* x     = (const float*)d_in[0];
    const float* cosT  = (const float*)d_in[1];
    const float* sinT  = (const float*)d_in[2];
    const float* Wqkv  = (const float*)d_in[3];
    const float* Wproj = (const float*)d_in[4];

    u16* xb     = (u16*)d_ws;                          // 8192*1024
    u16* wqkvb  = xb + (size_t)8192 * 1024;            // 3072*1024
    u16* wprojb = wqkvb + (size_t)3072 * 1024;         // 1024*1024
    u16* Qb     = wprojb + (size_t)1024 * 1024;        // 64*2048*64
    u16* Kb     = Qb + (size_t)64 * 2048 * 64;         // 64*2048*64
    f16* Vtg    = (f16*)(Kb + (size_t)64 * 2048 * 64); // 64*64*2048 (transposed)
    u16* attn   = (u16*)(Vtg + (size_t)64 * 64 * 2048);// 8192*1024

    cvt3_f32_bf16<<<12288, 256, 0, stream>>>(x, xb, 2097152,
                                             Wqkv, wqkvb, 786432,
                                             Wproj, wprojb, 262144);

    gemm_qkv<<<dim3(64, 24), 256, 0, stream>>>(xb, wqkvb, cosT, sinT, Qb, Kb, Vtg);
    flash<<<512, 256, 0, stream>>>(Qb, Kb, Vtg, attn);
    gemm_bt<<<dim3(64, 8), 256, 0, stream>>>(attn, wprojb, (float*)d_out, 8192, 1024, 1024);
}

// Round 21
// 262.146 us; speedup vs baseline: 3.7456x; 3.7456x over previous
//
#include <hip/hip_runtime.h>

constexpr int Tq = 2048;
constexpr int Dq = 1024;

typedef __bf16 bf16x8 __attribute__((ext_vector_type(8)));
typedef float f32x4 __attribute__((ext_vector_type(4)));
typedef _Float16 f16;
typedef f16 f16x4 __attribute__((ext_vector_type(4)));
typedef unsigned short u16;
typedef u16 u16x4 __attribute__((ext_vector_type(4)));
typedef u16 u16x8 __attribute__((ext_vector_type(8)));

__device__ __forceinline__ u16 f2bf(float f) {
    unsigned int u = __float_as_uint(f);
    u += 0x7fffu + ((u >> 16) & 1u);   // RNE
    return (u16)(u >> 16);
}

// async global->LDS, 16B per lane. LDS dest must be wave-uniform base + lane*16.
__device__ __forceinline__ void gld_lds16(const void* g, void* l) {
    __builtin_amdgcn_global_load_lds(
        (const __attribute__((address_space(1))) unsigned int*)g,
        (__attribute__((address_space(3))) unsigned int*)l, 16, 0, 0);
}

// ---------------- fp32 -> bf16 conversion (grid-stride, 3 arrays) -----------
__global__ void cvt3_f32_bf16(const float* __restrict__ a, u16* __restrict__ oa, int na,
                              const float* __restrict__ b, u16* __restrict__ ob, int nb,
                              const float* __restrict__ c, u16* __restrict__ oc, int nc) {
    const int ntot = na + nb + nc;
    for (int i = blockIdx.x * 256 + threadIdx.x; i < ntot; i += 2048 * 256) {
        const float* in; u16* out; int j = i;
        if (j < na) { in = a; out = oa; }
        else if (j < na + nb) { in = b; out = ob; j -= na; }
        else { in = c; out = oc; j -= na + nb; }
        float4 v = ((const float4*)in)[j];
        u16x4 o;
        o.x = f2bf(v.x); o.y = f2bf(v.y); o.z = f2bf(v.z); o.w = f2bf(v.w);
        ((u16x4*)out)[j] = o;
    }
}

// ---------------- QKV GEMM with fused RoPE + scatter epilogue ----------------
// C[8192,3072] = xb * Wqkv^T. blockIdx.y: 0..7 -> Q (rope+scale), 8..15 -> K
// (rope), 16..23 -> V (transposed f16). A 128-col tile never straddles Q/K/V,
// and d & d+32 of one head land in the SAME lane (sub-tiles j and j+2).
__global__ __launch_bounds__(256) void gemm_qkv(const u16* __restrict__ A,
                                                const u16* __restrict__ B,
                                                const float* __restrict__ cosT,
                                                const float* __restrict__ sinT,
                                                u16* __restrict__ Qb,
                                                u16* __restrict__ Kb,
                                                f16* __restrict__ Vtg) {
    constexpr int K = 1024, N = 3072;
    __shared__ u16 As[128 * 32];
    __shared__ u16 Bs[128 * 32];
    const int t = threadIdx.x;
    const int lane = t & 63;
    const int wave = t >> 6;
    const int l16 = lane & 15;
    const int quad = lane >> 4;
    const int bm = blockIdx.x * 128;
    const int by = blockIdx.y;
    const int bn = by * 128;
    const int wm = (wave & 1) * 64;
    const int wn = (wave >> 1) * 64;
    const int srow = t >> 2;
    const int scol = (t & 3) * 8;

    f32x4 acc[4][4] = {};

    const u16* Ab = A + (size_t)(bm + srow) * K + scol;
    const u16* Bb = B + (size_t)(bn + srow) * K + scol;

    for (int k0 = 0; k0 < K; k0 += 32) {
        gld_lds16(Ab + k0,                    (char*)As + t * 16);
        gld_lds16(Ab + (size_t)64 * K + k0,   (char*)As + 4096 + t * 16);
        gld_lds16(Bb + k0,                    (char*)Bs + t * 16);
        gld_lds16(Bb + (size_t)64 * K + k0,   (char*)Bs + 4096 + t * 16);
        __syncthreads();

        bf16x8 af[4], bf[4];
#pragma unroll
        for (int i = 0; i < 4; i++) {
            af[i] = *(const bf16x8*)&As[(wm + i * 16 + l16) * 32 + quad * 8];
            bf[i] = *(const bf16x8*)&Bs[(wn + i * 16 + l16) * 32 + quad * 8];
        }
#pragma unroll
        for (int i = 0; i < 4; i++)
#pragma unroll
            for (int j = 0; j < 4; j++)
                acc[i][j] = __builtin_amdgcn_mfma_f32_16x16x32_bf16(af[i], bf[j], acc[i][j], 0, 0, 0);
        __syncthreads();
    }

    const int kind = by >> 3;                   // 0=Q 1=K 2=V
    if (kind < 2) {
        // rope: pairs (j, j+2) give (d, d+32) of head h in the same lane
        u16* Out = kind ? Kb : Qb;
        const float qscale = kind ? 1.f : 0.18033688011112042f;  // 0.125*log2(e)
        const int h = ((by & 7) << 1) + (wn >> 6);
#pragma unroll
        for (int i = 0; i < 4; i++)
#pragma unroll
            for (int r = 0; r < 4; r++) {
                const int gm = bm + wm + i * 16 + quad * 4 + r;
                const int b = gm >> 11, tt = gm & 2047;
                const size_t row = ((size_t)(b * 16 + h) * Tq + tt) * 64;
#pragma unroll
                for (int jj = 0; jj < 2; jj++) {
                    const int dd = jj * 16 + l16;            // 0..31
                    const float c = cosT[tt * 32 + dd];
                    const float s = sinT[tt * 32 + dd];
                    const float v1 = acc[i][jj][r];
                    const float v2 = acc[i][jj + 2][r];
                    Out[row + dd]      = f2bf((v1 * c - v2 * s) * qscale);
                    Out[row + dd + 32] = f2bf((v1 * s + v2 * c) * qscale);
                }
            }
    } else {
        // V: write transposed (bh, d, t) in f16; f16x4 contiguous along t
#pragma unroll
        for (int i = 0; i < 4; i++) {
            const int gm0 = bm + wm + i * 16 + quad * 4;
            const int b = gm0 >> 11, tt = gm0 & 2047;
#pragma unroll
            for (int j = 0; j < 4; j++) {
                const int col = wn + j * 16 + l16;           // 0..127
                const int h = ((by & 7) << 1) + (col >> 6);
                const int d = col & 63;
                f16x4 o = {(f16)acc[i][j][0], (f16)acc[i][j][1],
                           (f16)acc[i][j][2], (f16)acc[i][j][3]};
                *(f16x4*)&Vtg[((size_t)(b * 16 + h) * 64 + d) * Tq + tt] = o;
            }
        }
    }
}

// ---------------- GEMM: C[M,N] = A[M,K] * B[N,K]^T (m97 structure) ----------
__global__ __launch_bounds__(256) void gemm_bt(const u16* __restrict__ A,
                                               const u16* __restrict__ B,
                                               float* __restrict__ Cv,
                                               int M, int N, int K) {
    __shared__ u16 As[128 * 32];
    __shared__ u16 Bs[128 * 32];
    const int t = threadIdx.x;
    const int lane = t & 63;
    const int wave = t >> 6;
    const int l16 = lane & 15;
    const int quad = lane >> 4;
    const int bm = blockIdx.x * 128;
    const int bn = blockIdx.y * 128;
    const int wm = (wave & 1) * 64;
    const int wn = (wave >> 1) * 64;
    const int srow = t >> 2;
    const int scol = (t & 3) * 8;

    f32x4 acc[4][4] = {};

    const u16* Ab = A + (size_t)(bm + srow) * K + scol;
    const u16* Bb = B + (size_t)(bn + srow) * K + scol;

    for (int k0 = 0; k0 < K; k0 += 32) {
        gld_lds16(Ab + k0,                    (char*)As + t * 16);
        gld_lds16(Ab + (size_t)64 * K + k0,   (char*)As + 4096 + t * 16);
        gld_lds16(Bb + k0,                    (char*)Bs + t * 16);
        gld_lds16(Bb + (size_t)64 * K + k0,   (char*)Bs + 4096 + t * 16);
        __syncthreads();

        bf16x8 af[4], bf[4];
#pragma unroll
        for (int i = 0; i < 4; i++) {
            af[i] = *(const bf16x8*)&As[(wm + i * 16 + l16) * 32 + quad * 8];
            bf[i] = *(const bf16x8*)&Bs[(wn + i * 16 + l16) * 32 + quad * 8];
        }
#pragma unroll
        for (int i = 0; i < 4; i++)
#pragma unroll
            for (int j = 0; j < 4; j++)
                acc[i][j] = __builtin_amdgcn_mfma_f32_16x16x32_bf16(af[i], bf[j], acc[i][j], 0, 0, 0);
        __syncthreads();
    }

#pragma unroll
    for (int i = 0; i < 4; i++)
#pragma unroll
        for (int j = 0; j < 4; j++)
#pragma unroll
            for (int r = 0; r < 4; r++) {
                const int gm = bm + wm + i * 16 + quad * 4 + r;
                const int gn = bn + wn + j * 16 + l16;
                Cv[(size_t)gm * N + gn] = acc[i][j][r];
            }
}

// ---------------- flash attention: S^T form, constant-max softmax -----------
// l-denominator via MFMA ones-trick (non-masked tiles): one extra
// mfma(A=ones, B=pf) per tk computes sum_k P[k][i] fully cross-quad summed --
// replaces 16 VALU adds + combine per stream-tile and the end shuffles.
// Masked (diagonal) tiles keep the scalar path: l must INCLUDE the diagonal
// term while PV excludes it (== out - self_w*v).
template <bool MASK>
__device__ __forceinline__ void flash_tile(const u16* __restrict__ Ks,
                                           const f16* __restrict__ Vs,
                                           const bf16x8& qf0, const bf16x8& qf1,
                                           int l16, int quad, int i_loc,
                                           float& l_sc, f32x4& o_l, f32x4* o_acc) {
    f32x4 s[4];
    const int cp0 = quad ^ (l16 & 7);
    const int cp1 = (4 + quad) ^ (l16 & 7);
    __builtin_amdgcn_s_setprio(1);
#pragma unroll
    for (int tn = 0; tn < 4; tn++) {
        const int jrow = tn * 16 + l16;
        bf16x8 kf0 = *(const bf16x8*)&Ks[jrow * 64 + cp0 * 8];
        bf16x8 kf1 = *(const bf16x8*)&Ks[jrow * 64 + cp1 * 8];
        f32x4 z = {0.f, 0.f, 0.f, 0.f};
        z = __builtin_amdgcn_mfma_f32_16x16x32_bf16(kf0, qf0, z, 0, 0, 0);
        z = __builtin_amdgcn_mfma_f32_16x16x32_bf16(kf1, qf1, z, 0, 0, 0);
        s[tn] = z;
    }
    __builtin_amdgcn_s_setprio(0);
    if (MASK) {
        float rsa = 0.f;
#pragma unroll
        for (int tn = 0; tn < 4; tn++)
#pragma unroll
            for (int r = 0; r < 4; r++) {
                const int j_loc = tn * 16 + quad * 4 + r;
                float v = s[tn][r];
                if (j_loc > i_loc) v = -1e30f;     // causal mask
                float p = exp2f(v);
                rsa += p;                          // l includes the diagonal...
                if (j_loc == i_loc) p = 0.f;       // ...PV excludes it
                s[tn][r] = p;
            }
        l_sc += rsa;
    } else {
#pragma unroll
        for (int tn = 0; tn < 4; tn++)
#pragma unroll
            for (int r = 0; r < 4; r++)
                s[tn][r] = exp2f(s[tn][r]);
    }

    f16x4 pf[4];
#pragma unroll
    for (int tk = 0; tk < 4; tk++)
        pf[tk] = f16x4{(f16)s[tk][0], (f16)s[tk][1], (f16)s[tk][2], (f16)s[tk][3]};
    __builtin_amdgcn_s_setprio(1);
    if (!MASK) {
        const f16x4 ones = {(f16)1.f, (f16)1.f, (f16)1.f, (f16)1.f};
#pragma unroll
        for (int tk = 0; tk < 4; tk++)
            o_l = __builtin_amdgcn_mfma_f32_16x16x16f16(ones, pf[tk], o_l, 0, 0, 0);
    }
#pragma unroll
    for (int td = 0; td < 4; td++) {
        const int drow = td * 16 + l16;
#pragma unroll
        for (int tk = 0; tk < 4; tk++) {
            const int cp = (2 * tk + (quad >> 1)) ^ (l16 & 7);
            f16x4 vf = *(const f16x4*)&Vs[drow * 64 + cp * 8 + (quad & 1) * 4];
            o_acc[td] = __builtin_amdgcn_mfma_f32_16x16x16f16(vf, pf[tk], o_acc[td], 0, 0, 0);
        }
    }
    __builtin_amdgcn_s_setprio(0);
}

// Fused dual-stream tile (measured: conflicts -25%, flash 94.2 -> 87.0).
// 4-stream variant spilled to scratch (VGPR liveness ~180) -- caps at 2.
template <bool MASKA>
__device__ __forceinline__ void flash_tile2(const u16* __restrict__ Ks,
                                            const f16* __restrict__ Vs,
                                            const bf16x8& qa0, const bf16x8& qa1,
                                            const bf16x8& qb0, const bf16x8& qb1,
                                            int l16, int quad, int i_loc,
                                            float& lA_sc, f32x4& olA, f32x4* oA,
                                            f32x4& olB, f32x4* oB) {
    f32x4 sA[4], sB[4];
    const int cp0 = quad ^ (l16 & 7);
    const int cp1 = (4 + quad) ^ (l16 & 7);
    __builtin_amdgcn_s_setprio(1);
#pragma unroll
    for (int tn = 0; tn < 4; tn++) {
        const int jrow = tn * 16 + l16;
        bf16x8 kf0 = *(const bf16x8*)&Ks[jrow * 64 + cp0 * 8];
        bf16x8 kf1 = *(const bf16x8*)&Ks[jrow * 64 + cp1 * 8];
        f32x4 zA = {0.f, 0.f, 0.f, 0.f}, zB = {0.f, 0.f, 0.f, 0.f};
        zA = __builtin_amdgcn_mfma_f32_16x16x32_bf16(kf0, qa0, zA, 0, 0, 0);
        zB = __builtin_amdgcn_mfma_f32_16x16x32_bf16(kf0, qb0, zB, 0, 0, 0);
        zA = __builtin_amdgcn_mfma_f32_16x16x32_bf16(kf1, qa1, zA, 0, 0, 0);
        zB = __builtin_amdgcn_mfma_f32_16x16x32_bf16(kf1, qb1, zB, 0, 0, 0);
        sA[tn] = zA; sB[tn] = zB;
    }
    __builtin_amdgcn_s_setprio(0);
    if (MASKA) {
        float rsa = 0.f;
#pragma unroll
        for (int tn = 0; tn < 4; tn++)
#pragma unroll
            for (int r = 0; r < 4; r++) {
                const int j_loc = tn * 16 + quad * 4 + r;
                float vA = sA[tn][r];
                if (j_loc > i_loc) vA = -1e30f;
                float pA = exp2f(vA);
                rsa += pA;
                if (j_loc == i_loc) pA = 0.f;
                sA[tn][r] = pA;
                sB[tn][r] = exp2f(sB[tn][r]);
            }
        lA_sc += rsa;
    } else {
#pragma unroll
        for (int tn = 0; tn < 4; tn++)
#pragma unroll
            for (int r = 0; r < 4; r++) {
                sA[tn][r] = exp2f(sA[tn][r]);
                sB[tn][r] = exp2f(sB[tn][r]);
            }
    }

    f16x4 pfA[4], pfB[4];
#pragma unroll
    for (int tk = 0; tk < 4; tk++) {
        pfA[tk] = f16x4{(f16)sA[tk][0], (f16)sA[tk][1], (f16)sA[tk][2], (f16)sA[tk][3]};
        pfB[tk] = f16x4{(f16)sB[tk][0], (f16)sB[tk][1], (f16)sB[tk][2], (f16)sB[tk][3]};
    }
    __builtin_amdgcn_s_setprio(1);
    {
        const f16x4 ones = {(f16)1.f, (f16)1.f, (f16)1.f, (f16)1.f};
#pragma unroll
        for (int tk = 0; tk < 4; tk++) {
            if (!MASKA)
                olA = __builtin_amdgcn_mfma_f32_16x16x16f16(ones, pfA[tk], olA, 0, 0, 0);
            olB = __builtin_amdgcn_mfma_f32_16x16x16f16(ones, pfB[tk], olB, 0, 0, 0);
        }
    }
#pragma unroll
    for (int td = 0; td < 4; td++) {
        const int drow = td * 16 + l16;
#pragma unroll
        for (int tk = 0; tk < 4; tk++) {
            const int cp = (2 * tk + (quad >> 1)) ^ (l16 & 7);
            f16x4 vf = *(const f16x4*)&Vs[drow * 64 + cp * 8 + (quad & 1) * 4];
            oA[td] = __builtin_amdgcn_mfma_f32_16x16x16f16(vf, pfA[tk], oA[td], 0, 0, 0);
            oB[td] = __builtin_amdgcn_mfma_f32_16x16x16f16(vf, pfB[tk], oB[td], 0, 0, 0);
        }
    }
    __builtin_amdgcn_s_setprio(0);
}

// 256 threads = 4 waves; EACH wave owns the same 16-row slice of BOTH
// complementary q-tiles (A = x, B = 31-x) => every wave computes exactly 33
// tiles. Common range [0..qtA] uses flash_tile2 (ONE kf/vf load set feeds both
// streams); (qtA..qtB] is B-only flash_tile. KVBLK=128, ring-2 of 32KB buffers
// ([K0][K1][V0][V1] 8KB each) -> 64KB LDS, 2 blocks/CU. stage(n2+1) issued
// AFTER barrier(n2): WAR-safe. Gate = vmcnt(0)+barrier (stage(n2) retired,
// issued a full iteration earlier).
// XCD-swizzled: head bh entirely on XCD bh>>3 (KV working set = 4MB = L2).
__global__ __launch_bounds__(256, 2) void flash(const u16* __restrict__ Qb,
                                                const u16* __restrict__ Kb,
                                                const f16* __restrict__ Vtg,
                                                u16* __restrict__ Ob) {
    __shared__ __align__(16) char smem[65536];   // 2 x 32KB

    const int t = threadIdx.x, lane = t & 63, wave = t >> 6;   // wave 0..3
    const int l16 = lane & 15, quad = lane >> 4;
    const int i = blockIdx.x;                    // 0..1023
    const int xcd = i & 7, w = i >> 3;           // w: 0..127
    const int bh = xcd * 8 + (w >> 4);           // 8 heads per XCD
    const int b = bh >> 4, h = bh & 15;
    const int x = w & 15;
    const int qtA = x, qtB = 31 - x;             // this wave's TWO 64-query tiles
    const int q0a = qtA * 64, q0b = qtB * 64;
    const u16* Qp = Qb + (size_t)bh * Tq * 64;
    const u16* Kp = Kb + (size_t)bh * Tq * 64;
    const f16* Vp = Vtg + (size_t)bh * 64 * Tq;

    const int rowi = wave * 16 + l16;            // row slice within each tile
    bf16x8 qa0 = *(const bf16x8*)(Qp + (size_t)(q0a + rowi) * 64 + quad * 8);
    bf16x8 qa1 = *(const bf16x8*)(Qp + (size_t)(q0a + rowi) * 64 + 32 + quad * 8);
    bf16x8 qb0 = *(const bf16x8*)(Qp + (size_t)(q0b + rowi) * 64 + quad * 8);
    bf16x8 qb1 = *(const bf16x8*)(Qp + (size_t)(q0b + rowi) * 64 + 32 + quad * 8);
    // pin Q-frag loads complete so manual vmcnt bookkeeping below is exact
    asm volatile("s_waitcnt vmcnt(0)"
                 : "+v"(qa0), "+v"(qa1), "+v"(qb0), "+v"(qb1) :: "memory");

    float lA_sc = 0.f;                           // scalar part (masked tiles)
    f32x4 olA = {}, olB = {};                    // MFMA ones-trick l parts
    f32x4 oA[4] = {}, oB[4] = {};

    const int sr = t >> 3;                       // 0..31 (256 threads)
    const int sc = (t & 7) ^ (sr & 7);           // swizzled chunk slot
    const int i_tloc = wave * 16 + l16;          // query pos within either tile
    const int nt = 32 - x;                       // 64-tiles 0 .. 31-x
    const int nt2 = (nt + 1) >> 1;               // 128-iterations (9..16)

    auto stage = [&](int n2) {                   // 8 loads -> vmcnt +8
        const int j0 = n2 * 128;                 // staged rows <= 2047: in-bounds
        char* buf = smem + (n2 & 1) * 32768;
        gld_lds16(Kp + (size_t)(j0 + sr) * 64 + sc * 8,            buf + t * 16);
        gld_lds16(Kp + (size_t)(j0 + 32 + sr) * 64 + sc * 8,       buf + 4096 + t * 16);
        gld_lds16(Kp + (size_t)(j0 + 64 + sr) * 64 + sc * 8,       buf + 8192 + t * 16);
        gld_lds16(Kp + (size_t)(j0 + 96 + sr) * 64 + sc * 8,       buf + 12288 + t * 16);
        gld_lds16(Vp + (size_t)sr * Tq + j0 + sc * 8,              buf + 16384 + t * 16);
        gld_lds16(Vp + (size_t)(32 + sr) * Tq + j0 + sc * 8,       buf + 20480 + t * 16);
        gld_lds16(Vp + (size_t)sr * Tq + j0 + 64 + sc * 8,         buf + 24576 + t * 16);
        gld_lds16(Vp + (size_t)(32 + sr) * Tq + j0 + 64 + sc * 8,  buf + 28672 + t * 16);
    };

    stage(0);
    for (int n2 = 0; n2 < nt2; n2++) {
        // gate: stage(n2) retired (issued a full iteration ago)
        asm volatile("s_waitcnt vmcnt(0)\n\ts_barrier" ::: "memory");
        if (n2 + 1 < nt2) stage(n2 + 1);         // post-barrier: WAR-safe ring-2
        char* cb = smem + (n2 & 1) * 32768;
#pragma unroll
        for (int s = 0; s < 2; s++) {
            const int tile = n2 * 2 + s;
            const u16* Ks = (const u16*)(cb + s * 8192);
            const f16* Vs = (const f16*)(cb + 16384 + s * 8192);
            if (tile < qtA)
                flash_tile2<false>(Ks, Vs, qa0, qa1, qb0, qb1, l16, quad, i_tloc,
                                   lA_sc, olA, oA, olB, oB);
            else if (tile == qtA)
                flash_tile2<true>(Ks, Vs, qa0, qa1, qb0, qb1, l16, quad, i_tloc,
                                  lA_sc, olA, oA, olB, oB);
            else if (tile < qtB)
                flash_tile<false>(Ks, Vs, qb0, qb1, l16, quad, i_tloc, lA_sc, olB, oB);
            else if (tile == qtB) {
                // masked B tile: scalar l accumulates into its own slot
                float lB_sc = 0.f;
                f32x4 dummy = {};
                flash_tile<true>(Ks, Vs, qb0, qb1, l16, quad, i_tloc, lB_sc, dummy, oB);
                // fold the shuffled scalar part into olB lane-uniformly later:
                lB_sc += __shfl_xor(lB_sc, 16, 64);
                lB_sc += __shfl_xor(lB_sc, 32, 64);
                olB[0] += lB_sc;                 // olB[0] is the value we read
            }
        }
    }

    // stream A: scalar part (its masked tile) needs the cross-quad reduce
    lA_sc += __shfl_xor(lA_sc, 16, 64);
    lA_sc += __shfl_xor(lA_sc, 32, 64);
    const float ivA = 1.f / (olA[0] + lA_sc);
    const float ivB = 1.f / olB[0];

    // epilogue: O^T -> O via padded LDS (stride 72), coalesced bf16 stores.
    // 8 virtual wave-slots (4 waves x 2 streams) * 1152 u16 = 18KB.
    __syncthreads();                             // all waves done reading ring
    u16* Os = (u16*)smem;
#pragma unroll
    for (int td = 0; td < 4; td++) {
        u16x4 oa, ob;
#pragma unroll
        for (int r = 0; r < 4; r++) {
            oa[r] = f2bf(oA[td][r] * ivA);
            ob[r] = f2bf(oB[td][r] * ivB);
        }
        *(u16x4*)&Os[wave * 1152 + l16 * 72 + td * 16 + quad * 4] = oa;
        *(u16x4*)&Os[(4 + wave) * 1152 + l16 * 72 + td * 16 + quad * 4] = ob;
    }
    __syncthreads();
    const int oi = lane >> 2, od = (lane & 3) * 16;
    {   // stream A rows
        u16x8 r0 = *(const u16x8*)&Os[wave * 1152 + oi * 72 + od];
        u16x8 r1 = *(const u16x8*)&Os[wave * 1152 + oi * 72 + od + 8];
        const size_t orow = ((size_t)b * Tq + q0a + wave * 16 + oi) * Dq + h * 64 + od;
        *(u16x8*)&Ob[orow] = r0;
        *(u16x8*)&Ob[orow + 8] = r1;
    }
    {   // stream B rows
        u16x8 r0 = *(const u16x8*)&Os[(4 + wave) * 1152 + oi * 72 + od];
        u16x8 r1 = *(const u16x8*)&Os[(4 + wave) * 1152 + oi * 72 + od + 8];
        const size_t orow = ((size_t)b * Tq + q0b + wave * 16 + oi) * Dq + h * 64 + od;
        *(u16x8*)&Ob[orow] = r0;
        *(u16x8*)&Ob[orow + 8] = r1;
    }
}

// ---------------- launch ----------------
extern "C" void kernel_launch(void* const* d_in, const int* in_sizes, int n_in,
                              void* d_out, int out_size, void* d_ws, size_t ws_size,
                              hipStream_t stream) {
    const float* x     = (const float*)d_in[0];
    const float* cosT  = (const float*)d_in[1];
    const float* sinT  = (const float*)d_in[2];
    const float* Wqkv  = (const float*)d_in[3];
    const float* Wproj = (const float*)d_in[4];

    u16* xb     = (u16*)d_ws;                          // 8192*1024
    u16* wqkvb  = xb + (size_t)8192 * 1024;            // 3072*1024
    u16* wprojb = wqkvb + (size_t)3072 * 1024;         // 1024*1024
    u16* Qb     = wprojb + (size_t)1024 * 1024;        // 64*2048*64
    u16* Kb     = Qb + (size_t)64 * 2048 * 64;         // 64*2048*64
    f16* Vtg    = (f16*)(Kb + (size_t)64 * 2048 * 64); // 64*64*2048 (transposed)
    u16* attn   = (u16*)(Vtg + (size_t)64 * 64 * 2048);// 8192*1024

    cvt3_f32_bf16<<<2048, 256, 0, stream>>>(x, xb, 2097152,
                                            Wqkv, wqkvb, 786432,
                                            Wproj, wprojb, 262144);

    gemm_qkv<<<dim3(64, 24), 256, 0, stream>>>(xb, wqkvb, cosT, sinT, Qb, Kb, Vtg);
    flash<<<1024, 256, 0, stream>>>(Qb, Kb, Vtg, attn);
    gemm_bt<<<dim3(64, 8), 256, 0, stream>>>(attn, wprojb, (float*)d_out, 8192, 1024, 1024);
}